// Round 17
// baseline (688.182 us; speedup 1.0000x reference)
//
#include <hip/hip_runtime.h>
#include <hip/hip_bf16.h>

#define NB 8
#define NP 8192
#define NC 6
#define NG 512
#define GS 32

#define CENTER_OFF (NB * NG * GS * NC)        /* 786432 */
#define IDX_OFF    (CENTER_OFF + NB * NG * 3) /* 798720 */

// Dtypes (validated R6-R16): d_in[0] f32, d_out f32; _rn math in the
// reference's association order. fps = (max dist, tie -> min idx);
// knn = (min d2, tie -> min idx) == lax.top_k stable order.
// LAW (R11/R12/R16): three structurally different knn rewrites sharing the
// early-flip u32 local-compare produced the identical deterministic absmax
// 48.0; mechanism unlocated. Only the R8 float-compare knn is proven exact
// (absmax 0.0 in R8/R13/R15) — it is frozen below. fps selection machinery
// (raw-bits u32 wave key, DPP+ballot) is separately validated exact.
// R17 fps: post-loop 31-op max tree -> 4 in-loop running fmaxf accumulators
// (serial tail removed; exactness preserved: m is exact max, and first-j
// comes from the unchanged mask+ctz).

#define DPP_MAX_U32(v, ctrl)                                               \
  {                                                                        \
    unsigned _m = (unsigned)__builtin_amdgcn_update_dpp(                   \
        (int)(v), (int)(v), (ctrl), 0xf, 0xf, false);                      \
    (v) = (_m > (v)) ? _m : (v);                                           \
  }

// ---------------------------------------------------------------------------
// Kernel 1: FPS. 256 thr (4 waves, 1/SIMD), 32 pts/thread.
// Per iter: merge 4 running maxima (3 fmaxf) -> mask+ctz first-j -> DPP u32
// max + ballot arg-resolve -> lane0 ds_write -> ONE parity barrier ->
// 4-partial u64 register tree -> float4 mir gather -> _rn min-update with
// interleaved macc tracking. No global ops in the loop.
// ---------------------------------------------------------------------------
__global__ __launch_bounds__(256) void fps_kernel(
    const float* __restrict__ xyz, float* __restrict__ out,
    int* __restrict__ cidx)
{
  __shared__ float4 mir[NP];                    // 128 KB point mirror
  __shared__ unsigned long long kpart[2][4];
  __shared__ int sel[NG];

  const int b = blockIdx.x;
  const int tid = threadIdx.x;
  const int lane = tid & 63;
  const int wave = tid >> 6;
  const float* base = xyz + (size_t)b * NP * NC;

  float px[32], py[32], pz[32], dv[32];
#pragma unroll
  for (int j = 0; j < 32; ++j) {
    const int p = tid + (j << 8);
    px[j] = base[p * 6 + 0];
    py[j] = base[p * 6 + 1];
    pz[j] = base[p * 6 + 2];
    mir[p] = make_float4(px[j], py[j], pz[j], 0.0f);
  }
  if (tid == 0) sel[0] = 0;
  __syncthreads();

  float4 c0 = mir[0];
  float cx = c0.x, cy = c0.y, cz = c0.z;

  // initial distances + interleaved running maxima (4 chains of 8)
  float ma0 = 0.0f, ma1 = 0.0f, ma2 = 0.0f, ma3 = 0.0f;  // dv >= 0
#pragma unroll
  for (int j = 0; j < 32; ++j) {
    const float dx = __fsub_rn(px[j], cx);
    const float dy = __fsub_rn(py[j], cy);
    const float dz = __fsub_rn(pz[j], cz);
    dv[j] = __fadd_rn(
        __fadd_rn(__fmul_rn(dx, dx), __fmul_rn(dy, dy)), __fmul_rn(dz, dz));
    if ((j & 3) == 0) ma0 = fmaxf(ma0, dv[j]);
    else if ((j & 3) == 1) ma1 = fmaxf(ma1, dv[j]);
    else if ((j & 3) == 2) ma2 = fmaxf(ma2, dv[j]);
    else ma3 = fmaxf(ma3, dv[j]);
  }

  for (int it = 1; it < NG; ++it) {
    // exact max of dv[0..31] (fmaxf of non-negatives returns an input)
    const float m = fmaxf(fmaxf(ma0, ma1), fmaxf(ma2, ma3));
    // first j with dv[j]==m -> min point idx (tie-safe regardless of how m
    // was computed)
    unsigned mask = 0;
#pragma unroll
    for (int j = 0; j < 32; ++j)
      mask |= (dv[j] == m) ? (1u << j) : 0u;
    const int jj = __builtin_ctz(mask);
    const unsigned lo = (unsigned)(NP - 1 - tid - (jj << 8));  // 8191 - p

    // wave max of m's bits (dv>=0: u32 order == f32 order)
    const unsigned sv = __float_as_uint(m);
    unsigned r = sv;
    DPP_MAX_U32(r, 0x111); DPP_MAX_U32(r, 0x112); DPP_MAX_U32(r, 0x114);
    DPP_MAX_U32(r, 0x118); DPP_MAX_U32(r, 0x142); DPP_MAX_U32(r, 0x143);
    const unsigned smax = (unsigned)__builtin_amdgcn_readlane((int)r, 63);

    const unsigned long long mk = __ballot(sv == smax);
    unsigned wlo;
    if (mk & (mk - 1)) {          // lane tie: max lo = min point idx
      unsigned long long mm = mk; unsigned best = 0;
      while (mm) {
        const int l = __builtin_ctzll(mm);
        const unsigned c = (unsigned)__builtin_amdgcn_readlane((int)lo, l);
        if (c > best) best = c;
        mm &= mm - 1;
      }
      wlo = best;
    } else {
      wlo = (unsigned)__builtin_amdgcn_readlane((int)lo, __builtin_ctzll(mk));
    }

    const int pb = it & 1;
    if (lane == 0)
      kpart[pb][wave] = ((unsigned long long)smax << 32) | wlo;
    __syncthreads();

    const unsigned long long* kp = kpart[pb];
    unsigned long long g0 = kp[0] > kp[1] ? kp[0] : kp[1];
    unsigned long long g1 = kp[2] > kp[3] ? kp[2] : kp[3];
    g0 = g0 > g1 ? g0 : g1;
    const int gi = (NP - 1) - (int)(unsigned)(g0 & 0xFFFFFFFFu);
    if (tid == 0) sel[it] = gi;

    const float4 c = mir[gi];     // one ds_read_b128 broadcast
    cx = c.x; cy = c.y; cz = c.z;

    // min-update + interleaved running maxima for the next iteration
    ma0 = 0.0f; ma1 = 0.0f; ma2 = 0.0f; ma3 = 0.0f;
#pragma unroll
    for (int j = 0; j < 32; ++j) {
      const float dx = __fsub_rn(px[j], cx);
      const float dy = __fsub_rn(py[j], cy);
      const float dz = __fsub_rn(pz[j], cz);
      const float d = __fadd_rn(
          __fadd_rn(__fmul_rn(dx, dx), __fmul_rn(dy, dy)), __fmul_rn(dz, dz));
      dv[j] = fminf(dv[j], d);
      if ((j & 3) == 0) ma0 = fmaxf(ma0, dv[j]);
      else if ((j & 3) == 1) ma1 = fmaxf(ma1, dv[j]);
      else if ((j & 3) == 2) ma2 = fmaxf(ma2, dv[j]);
      else ma3 = fmaxf(ma3, dv[j]);
    }
  }
  __syncthreads();

  for (int g = tid; g < NG; g += 256) {
    const int p = sel[g];
    const float4 c = mir[p];
    const size_t cb = (size_t)(b * NG + g) * 3;
    out[CENTER_OFF + cb + 0] = c.x;
    out[CENTER_OFF + cb + 1] = c.y;
    out[CENTER_OFF + cb + 2] = c.z;
    cidx[b * NG + g] = p;
  }
}

// ---------------------------------------------------------------------------
// Kernel 2: 32-NN — R8-validated version, FROZEN (absmax 0.0 in R8/R13/R15).
// Float-domain local compares; flip only on the selected local min.
// ---------------------------------------------------------------------------
__global__ __launch_bounds__(256) void knn_kernel(
    const float* __restrict__ xyz, float* __restrict__ out,
    const int* __restrict__ cidx)
{
  __shared__ unsigned long long kpart[2][4];

  const int bg = blockIdx.x;
  const int b = bg >> 9;
  const int tid = threadIdx.x;
  const int lane = tid & 63;
  const int wave = tid >> 6;
  const float* base = xyz + (size_t)b * NP * NC;

  const int pc = cidx[bg] & (NP - 1);  // clamp: fault-proof under any state
  const float cx = base[pc * 6 + 0];
  const float cy = base[pc * 6 + 1];
  const float cz = base[pc * 6 + 2];
  const float cc = __fadd_rn(
      __fadd_rn(__fmul_rn(cx, cx), __fmul_rn(cy, cy)), __fmul_rn(cz, cz));

  float dreg[32];
  float lv = __builtin_inff();
  int   li = 0x7fffffff;
#pragma unroll
  for (int j = 0; j < 32; ++j) {
    const int p = tid + (j << 8);
    const float x = base[p * 6 + 0];
    const float y = base[p * 6 + 1];
    const float z = base[p * 6 + 2];
    const float xx = __fadd_rn(
        __fadd_rn(__fmul_rn(x, x), __fmul_rn(y, y)), __fmul_rn(z, z));
    const float dot = __fadd_rn(
        __fadd_rn(__fmul_rn(cx, x), __fmul_rn(cy, y)), __fmul_rn(cz, z));
    const float d2 = __fsub_rn(__fadd_rn(cc, xx), __fmul_rn(2.0f, dot));
    dreg[j] = d2;
    if (d2 < lv) { lv = d2; li = p; }  // strict <: first min (lowest index)
  }

  int myp = 0;
  for (int k = 0; k < GS; ++k) {
    unsigned u = __float_as_uint(lv);
    u ^= ((unsigned)((int)u >> 31)) | 0x80000000u;
    unsigned long long key = ((unsigned long long)u << 32) | (unsigned)li;
#pragma unroll
    for (int off = 32; off; off >>= 1) {
      const unsigned long long ok = __shfl_xor(key, off);
      if (ok < key) key = ok;
    }
    const int pb = k & 1;
    if (lane == 0) kpart[pb][wave] = key;
    __syncthreads();

    unsigned long long g = kpart[pb][lane & 3];
#pragma unroll
    for (int off = 1; off < 4; off <<= 1) {
      const unsigned long long og = __shfl_xor(g, off);
      if (og < g) g = og;
    }
    const int p = (int)(unsigned)(g & 0xFFFFFFFFu);
    if (tid == k) myp = p;

    if ((p & 255) == tid) {
      const int wj = p >> 8;
      lv = __builtin_inff(); li = 0x7fffffff;
#pragma unroll
      for (int j = 0; j < 32; ++j) {
        if (j == wj) dreg[j] = __builtin_inff();
        if (dreg[j] < lv) { lv = dreg[j]; li = tid + (j << 8); }
      }
    }
  }

  if (tid < GS) {
    const int p = myp & (NP - 1);  // in-bounds by construction
    const float v0 = base[p * 6 + 0];
    const float v1 = base[p * 6 + 1];
    const float v2 = base[p * 6 + 2];
    const size_t ob = ((size_t)bg * GS + tid) * 6;
    out[ob + 0] = __fsub_rn(v0, cx);
    out[ob + 1] = __fsub_rn(v1, cy);
    out[ob + 2] = __fsub_rn(v2, cz);
    out[ob + 3] = base[p * 6 + 3];  // extras: raw f32 passthrough
    out[ob + 4] = base[p * 6 + 4];
    out[ob + 5] = base[p * 6 + 5];
    out[IDX_OFF + (size_t)bg * GS + tid] = (float)p;  // idx as f32 value
  }
}

extern "C" void kernel_launch(void* const* d_in, const int* in_sizes, int n_in,
                              void* d_out, int out_size, void* d_ws,
                              size_t ws_size, hipStream_t stream)
{
  const float* xyz = (const float*)d_in[0];
  float* out = (float*)d_out;
  int* cidx = (int*)d_ws;  // NB*NG ints = 16 KiB scratch

  hipLaunchKernelGGL(fps_kernel, dim3(NB), dim3(256), 0, stream,
                     xyz, out, cidx);
  hipLaunchKernelGGL(knn_kernel, dim3(NB * NG), dim3(256), 0, stream,
                     xyz, out, cidx);
}